// Round 1
// baseline (957.012 us; speedup 1.0000x reference)
//
#include <hip/hip_runtime.h>
#include <hip/hip_bf16.h>

// CornerPool on MI355X: bf16 MFMA implicit-GEMM convs in NHWC, fused BN/ReLU,
// in-place reverse cummax pools, final conv writes NCHW fp32 directly.

using bf16x8  = __attribute__((ext_vector_type(8))) __bf16;
using floatx4 = __attribute__((ext_vector_type(4))) float;

__device__ __forceinline__ float bf2f(__hip_bfloat16 h) { return __bfloat162float(h); }
__device__ __forceinline__ __hip_bfloat16 f2bf(float f) { return __float2bfloat16(f); }

// ---------------- prep kernels ----------------

// x: [8][256][128][128] fp32 NCHW -> xb: [8][128][128][256] bf16 NHWC
__global__ __launch_bounds__(256) void k_cast_x(const float* __restrict__ x,
                                                __hip_bfloat16* __restrict__ xb) {
    __shared__ float t[64][65];
    const int n  = blockIdx.z;
    const int h  = blockIdx.y;
    const int c0 = (blockIdx.x >> 1) * 64;
    const int w0 = (blockIdx.x & 1) * 64;
    const int tid = threadIdx.x;
#pragma unroll
    for (int it = 0; it < 16; ++it) {
        int idx = it * 256 + tid;
        int c = idx >> 6, w = idx & 63;
        t[c][w] = x[(((size_t)n * 256 + c0 + c) * 128 + h) * 128 + w0 + w];
    }
    __syncthreads();
#pragma unroll
    for (int it = 0; it < 16; ++it) {
        int idx = it * 256 + tid;
        int w = idx >> 6, c = idx & 63;
        xb[(((size_t)n * 128 + h) * 128 + w0 + w) * 256 + c0 + c] = f2bf(t[c][w]);
    }
}

// OIHW fp32 -> [co][tap][ci] bf16 (tap = kh*3+kw; taps==1 -> plain cast)
__global__ void k_reorder_w(const float* __restrict__ src, __hip_bfloat16* __restrict__ dst,
                            int Cin, int taps, int total) {
    int i = blockIdx.x * 256 + threadIdx.x;
    if (i >= total) return;
    int ci  = i % Cin;
    int tap = (i / Cin) % taps;
    int co  = i / (Cin * taps);
    dst[i] = f2bf(src[((size_t)co * Cin + ci) * taps + tap]);
}

// bn params [4][C] -> sb: [C] scale, [C] bias
__global__ void k_prep_bn(const float* __restrict__ p, float* __restrict__ sb, int C) {
    int i = blockIdx.x * 64 + threadIdx.x;
    if (i >= C) return;
    float g = p[i], b = p[C + i], m = p[2 * C + i], v = p[3 * C + i];
    float s = g / sqrtf(v + 1e-5f);
    sb[i] = s;
    sb[C + i] = b - m * s;
}

// ---------------- pools (NHWC bf16, C=64, in-place) ----------------

// reverse cummax over h; buf [8][128][128][64]
__global__ __launch_bounds__(256) void k_pool1(__hip_bfloat16* __restrict__ b) {
    const int idx = blockIdx.x * 256 + threadIdx.x; // 8*128*64 = 65536
    const int c = idx & 63;
    const int w = (idx >> 6) & 127;
    const int n = idx >> 13;
    const size_t stride = 128 * 64;
    const size_t base = ((size_t)n * 128 * 128 + w) * 64 + c;
    float m = 0.0f; // inputs are post-relu, >= 0
    for (int hb = 31; hb >= 0; --hb) {
        size_t a0 = base + (size_t)(4 * hb) * stride;
        float v0 = bf2f(b[a0]);
        float v1 = bf2f(b[a0 + stride]);
        float v2 = bf2f(b[a0 + 2 * stride]);
        float v3 = bf2f(b[a0 + 3 * stride]);
        float m3 = fmaxf(m, v3);
        float m2 = fmaxf(m3, v2);
        float m1 = fmaxf(m2, v1);
        float m0 = fmaxf(m1, v0);
        b[a0 + 3 * stride] = f2bf(m3);
        b[a0 + 2 * stride] = f2bf(m2);
        b[a0 + stride]     = f2bf(m1);
        b[a0]              = f2bf(m0);
        m = m0;
    }
}

// reverse cummax over w of b, then b = cummax + pl (pool sum), in place
__global__ __launch_bounds__(256) void k_pool2(__hip_bfloat16* __restrict__ b,
                                               const __hip_bfloat16* __restrict__ pl) {
    const int idx = blockIdx.x * 256 + threadIdx.x; // 8*128*64
    const int c = idx & 63;
    const int h = (idx >> 6) & 127;
    const int n = idx >> 13;
    const size_t base = (((size_t)n * 128 + h) * 128) * 64 + c;
    float m = 0.0f;
    for (int wb = 31; wb >= 0; --wb) {
        size_t a0 = base + (size_t)(4 * wb) * 64;
        float v0 = bf2f(b[a0]);
        float v1 = bf2f(b[a0 + 64]);
        float v2 = bf2f(b[a0 + 128]);
        float v3 = bf2f(b[a0 + 192]);
        float u0 = bf2f(pl[a0]);
        float u1 = bf2f(pl[a0 + 64]);
        float u2 = bf2f(pl[a0 + 128]);
        float u3 = bf2f(pl[a0 + 192]);
        float m3 = fmaxf(m, v3);
        float m2 = fmaxf(m3, v2);
        float m1 = fmaxf(m2, v1);
        float m0 = fmaxf(m1, v0);
        b[a0 + 192] = f2bf(m3 + u3);
        b[a0 + 128] = f2bf(m2 + u2);
        b[a0 + 64]  = f2bf(m1 + u1);
        b[a0]       = f2bf(m0 + u0);
        m = m0;
    }
}

// ---------------- implicit-GEMM conv ----------------
// GEMM: D[p][co] = sum_k Im2col[p][k] * W[co][k], k = tap*CIN + ci
// xin NHWC bf16 [8][128][128][CIN]; wgt [Cout][TAPS*CIN] bf16; sb [Cout]scale+[Cout]bias
// MODE 0: BN            -> bf16 NHWC out
// MODE 1: BN+relu       -> bf16 NHWC out
// MODE 2: BN +res, relu -> bf16 NHWC out
// MODE 3: BN+relu       -> fp32 NCHW out (operands swapped: D[co][p])
template <int BM, int BN, int CIN, int TAPS, int MODE>
__global__ __launch_bounds__(256) void conv_mfma(const __hip_bfloat16* __restrict__ xin,
                                                 const __hip_bfloat16* __restrict__ wgt,
                                                 const float* __restrict__ sb,
                                                 void* __restrict__ out,
                                                 const __hip_bfloat16* __restrict__ resbuf,
                                                 int Cout) {
    constexpr int K = TAPS * CIN;
    __shared__ __align__(16) __hip_bfloat16 Xs[BM * 64];
    __shared__ __align__(16) __hip_bfloat16 Ws[BN * 64];
    const int tid  = threadIdx.x;
    const int lane = tid & 63;
    const int wid  = tid >> 6;
    constexpr int NWN = BN / 64; // waves along co
    const int wm = wid / NWN;
    const int wn = wid % NWN;
    const int p0 = blockIdx.x * BM;
    const int c0 = blockIdx.y * BN;
    const int q   = lane >> 4;
    const int r16 = lane & 15;

    floatx4 acc[4][4] = {};

    for (int k0 = 0; k0 < K; k0 += 64) {
        const int tap = (TAPS == 1) ? 0 : (k0 / CIN);
        const int ci0 = k0 % CIN;
        const int dh  = (TAPS == 1) ? 0 : (tap / 3 - 1);
        const int dw  = (TAPS == 1) ? 0 : (tap % 3 - 1);

        // stage X tile: BM rows x 64 k; each thread 16B per iter, swizzled by row
#pragma unroll
        for (int it = 0; it < BM / 32; ++it) {
            const int pp = it * 32 + (tid >> 3);
            const int g  = tid & 7;
            const int P  = p0 + pp;
            const int w  = P & 127;
            const int nh = P >> 7;
            const int h  = nh & 127;
            const int n  = nh >> 7;
            const int hh = h + dh;
            const int ww = w + dw;
            uint4 val = make_uint4(0u, 0u, 0u, 0u);
            if (TAPS == 1 || ((unsigned)hh < 128u && (unsigned)ww < 128u)) {
                val = *(const uint4*)(xin + (((size_t)(n * 128 + hh) * 128 + ww) * CIN + ci0 + g * 8));
            }
            *(uint4*)(&Xs[pp * 64 + (((g + pp) & 7) * 8)]) = val;
        }
        // stage W tile: BN rows x 64 k
#pragma unroll
        for (int it = 0; it < BN / 32; ++it) {
            const int rr = it * 32 + (tid >> 3);
            const int g  = tid & 7;
            uint4 val = *(const uint4*)(wgt + ((size_t)(c0 + rr) * K + k0 + g * 8));
            *(uint4*)(&Ws[rr * 64 + (((g + rr) & 7) * 8)]) = val;
        }
        __syncthreads();

#pragma unroll
        for (int ks = 0; ks < 2; ++ks) {
            bf16x8 afr[4], bfr[4];
#pragma unroll
            for (int i = 0; i < 4; ++i) {
                const int pp = wm * 64 + i * 16 + r16;
                const int g  = ks * 4 + q;
                afr[i] = *(const bf16x8*)(&Xs[pp * 64 + (((g + pp) & 7) * 8)]);
            }
#pragma unroll
            for (int j = 0; j < 4; ++j) {
                const int rr = wn * 64 + j * 16 + r16;
                const int g  = ks * 4 + q;
                bfr[j] = *(const bf16x8*)(&Ws[rr * 64 + (((g + rr) & 7) * 8)]);
            }
#pragma unroll
            for (int i = 0; i < 4; ++i)
#pragma unroll
                for (int j = 0; j < 4; ++j) {
                    if (MODE == 3)
                        acc[i][j] = __builtin_amdgcn_mfma_f32_16x16x32_bf16(bfr[i], afr[j], acc[i][j], 0, 0, 0);
                    else
                        acc[i][j] = __builtin_amdgcn_mfma_f32_16x16x32_bf16(afr[i], bfr[j], acc[i][j], 0, 0, 0);
                }
        }
        __syncthreads();
    }

    if (MODE != 3) {
        __hip_bfloat16* o = (__hip_bfloat16*)out;
#pragma unroll
        for (int j = 0; j < 4; ++j) {
            const int co = c0 + wn * 64 + j * 16 + r16;
            const float s  = sb[co];
            const float bi = sb[Cout + co];
#pragma unroll
            for (int i = 0; i < 4; ++i) {
                const int pb = p0 + wm * 64 + i * 16 + q * 4;
#pragma unroll
                for (int r = 0; r < 4; ++r) {
                    float v = acc[i][j][r] * s + bi;
                    if (MODE == 2) v += bf2f(resbuf[(size_t)(pb + r) * Cout + co]);
                    if (MODE >= 1) v = fmaxf(v, 0.0f);
                    o[(size_t)(pb + r) * Cout + co] = f2bf(v);
                }
            }
        }
    } else {
        float* o = (float*)out;
#pragma unroll
        for (int i = 0; i < 4; ++i) {
#pragma unroll
            for (int r = 0; r < 4; ++r) {
                const int co = c0 + wn * 64 + i * 16 + q * 4 + r;
                const float s  = sb[co];
                const float bi = sb[Cout + co];
#pragma unroll
                for (int j = 0; j < 4; ++j) {
                    const int p  = p0 + wm * 64 + j * 16 + r16;
                    const int ww = p & 127;
                    const int nh = p >> 7;
                    const int h  = nh & 127;
                    const int n  = nh >> 7;
                    float v = fmaxf(acc[i][j][r] * s + bi, 0.0f);
                    o[(((size_t)(n * 256 + co)) * 128 + h) * 128 + ww] = v;
                }
            }
        }
    }
}

// ---------------- launcher ----------------

extern "C" void kernel_launch(void* const* d_in, const int* in_sizes, int n_in,
                              void* d_out, int out_size, void* d_ws, size_t ws_size,
                              hipStream_t stream) {
    const float* x       = (const float*)d_in[0];
    const float* w_res   = (const float*)d_in[1];
    const float* bn_res  = (const float*)d_in[2];
    const float* w_vpre  = (const float*)d_in[3];
    const float* bn_vpre = (const float*)d_in[4];
    const float* w_hpre  = (const float*)d_in[5];
    const float* bn_hpre = (const float*)d_in[6];
    const float* w_add   = (const float*)d_in[7];
    const float* bn_add  = (const float*)d_in[8];
    const float* w_post  = (const float*)d_in[9];
    const float* bn_post = (const float*)d_in[10];

    const size_t SZ_XB = (size_t)8 * 128 * 128 * 256 * 2; // 67108864
    const size_t SZ_P  = (size_t)8 * 128 * 128 * 64 * 2;  // 16777216

    char* w = (char*)d_ws;
    __hip_bfloat16* xb   = (__hip_bfloat16*)(w);                      // also reused as outbuf
    __hip_bfloat16* resb = (__hip_bfloat16*)(w + SZ_XB);
    __hip_bfloat16* p1   = (__hip_bfloat16*)(w + 2 * SZ_XB);
    __hip_bfloat16* p2   = (__hip_bfloat16*)(w + 2 * SZ_XB + SZ_P);
    char* wp = w + 2 * SZ_XB + 2 * SZ_P;
    __hip_bfloat16* wres  = (__hip_bfloat16*)wp; wp += (size_t)65536 * 2;
    __hip_bfloat16* wvpre = (__hip_bfloat16*)wp; wp += (size_t)147456 * 2;
    __hip_bfloat16* whpre = (__hip_bfloat16*)wp; wp += (size_t)147456 * 2;
    __hip_bfloat16* wadd  = (__hip_bfloat16*)wp; wp += (size_t)147456 * 2;
    __hip_bfloat16* wpost = (__hip_bfloat16*)wp; wp += (size_t)589824 * 2;
    float* sb_res  = (float*)wp; wp += 512 * 4;
    float* sb_vpre = (float*)wp; wp += 128 * 4;
    float* sb_hpre = (float*)wp; wp += 128 * 4;
    float* sb_add  = (float*)wp; wp += 512 * 4;
    float* sb_post = (float*)wp; wp += 512 * 4;

    // weight + BN prep (tiny)
    k_reorder_w<<<256, 256, 0, stream>>>(w_res, wres, 256, 1, 65536);
    k_reorder_w<<<576, 256, 0, stream>>>(w_vpre, wvpre, 256, 9, 147456);
    k_reorder_w<<<576, 256, 0, stream>>>(w_hpre, whpre, 256, 9, 147456);
    k_reorder_w<<<576, 256, 0, stream>>>(w_add, wadd, 64, 9, 147456);
    k_reorder_w<<<2304, 256, 0, stream>>>(w_post, wpost, 256, 9, 589824);
    k_prep_bn<<<4, 64, 0, stream>>>(bn_res, sb_res, 256);
    k_prep_bn<<<1, 64, 0, stream>>>(bn_vpre, sb_vpre, 64);
    k_prep_bn<<<1, 64, 0, stream>>>(bn_hpre, sb_hpre, 64);
    k_prep_bn<<<4, 64, 0, stream>>>(bn_add, sb_add, 256);
    k_prep_bn<<<4, 64, 0, stream>>>(bn_post, sb_post, 256);

    // x -> NHWC bf16
    k_cast_x<<<dim3(8, 128, 8), 256, 0, stream>>>(x, xb);

    // res = BN(conv1x1(x))                      -> resb (bf16 NHWC, C=256)
    conv_mfma<128, 128, 256, 1, 0><<<dim3(1024, 2), 256, 0, stream>>>(xb, wres, sb_res, resb, nullptr, 256);
    // p1 = relu(BN(conv3x3(x, w_vpre)))         -> p1 (bf16 NHWC, C=64)
    conv_mfma<256, 64, 256, 9, 1><<<dim3(512, 1), 256, 0, stream>>>(xb, wvpre, sb_vpre, p1, nullptr, 64);
    // p2 = relu(BN(conv3x3(x, w_hpre)))         -> p2
    conv_mfma<256, 64, 256, 9, 1><<<dim3(512, 1), 256, 0, stream>>>(xb, whpre, sb_hpre, p2, nullptr, 64);
    // pool1 in place on p1; pool2 in place on p2, fused add -> p2 = pool1+pool2
    k_pool1<<<256, 256, 0, stream>>>(p1);
    k_pool2<<<256, 256, 0, stream>>>(p2, p1);
    // merged = BN(conv3x3(p2, w_add)); out = relu(res+merged) -> xb region (bf16 NHWC, C=256)
    conv_mfma<128, 128, 64, 9, 2><<<dim3(1024, 2), 256, 0, stream>>>(p2, wadd, sb_add, xb, resb, 256);
    // final = relu(BN(conv3x3(out, w_post)))    -> d_out fp32 NCHW
    conv_mfma<128, 128, 256, 9, 3><<<dim3(1024, 2), 256, 0, stream>>>(xb, wpost, sb_post, d_out, nullptr, 256);
}

// Round 2
// 933.892 us; speedup vs baseline: 1.0248x; 1.0248x over previous
//
#include <hip/hip_runtime.h>
#include <hip/hip_bf16.h>

// CornerPool on MI355X, round 2: halo-staged implicit-GEMM 3x3 convs
// (stage 3 input rows per ci-chunk once, run all 9 taps from LDS),
// fused vpre+hpre, BN scale folded into bf16 weights.

using bf16x8  = __attribute__((ext_vector_type(8))) __bf16;
using floatx4 = __attribute__((ext_vector_type(4))) float;

__device__ __forceinline__ float bf2f(__hip_bfloat16 h) { return __bfloat162float(h); }
__device__ __forceinline__ __hip_bfloat16 f2bf(float f) { return __float2bfloat16(f); }

// ---------------- prep kernels ----------------

// x: [8][256][128][128] fp32 NCHW -> xb: [8][128][128][256] bf16 NHWC
__global__ __launch_bounds__(256) void k_cast_x(const float* __restrict__ x,
                                                __hip_bfloat16* __restrict__ xb) {
    __shared__ float t[64][65];
    const int n  = blockIdx.z;
    const int h  = blockIdx.y;
    const int c0 = (blockIdx.x >> 1) * 64;
    const int w0 = (blockIdx.x & 1) * 64;
    const int tid = threadIdx.x;
#pragma unroll
    for (int it = 0; it < 16; ++it) {
        int idx = it * 256 + tid;
        int c = idx >> 6, w = idx & 63;
        t[c][w] = x[(((size_t)n * 256 + c0 + c) * 128 + h) * 128 + w0 + w];
    }
    __syncthreads();
#pragma unroll
    for (int it = 0; it < 16; ++it) {
        int idx = it * 256 + tid;
        int w = idx >> 6, c = idx & 63;
        xb[(((size_t)n * 128 + h) * 128 + w0 + w) * 256 + c0 + c] = f2bf(t[c][w]);
    }
}

// bn params [4][C] -> scale[C], bias[C]
__global__ void k_prep_bn(const float* __restrict__ p, float* __restrict__ sc,
                          float* __restrict__ bi, int C) {
    int i = blockIdx.x * 64 + threadIdx.x;
    if (i >= C) return;
    float g = p[i], b = p[C + i], m = p[2 * C + i], v = p[3 * C + i];
    float s = g / sqrtf(v + 1e-5f);
    sc[i] = s;
    bi[i] = b - m * s;
}

// 3x3: src fp32 [CoS][Cin][3][3] -> dst bf16 [tap][CoutTot][Cin] at co_off, scaled by BN scale
__global__ void k_reorder_w3(const float* __restrict__ src, __hip_bfloat16* __restrict__ dst,
                             const float* __restrict__ scale, int Cin, int CoutTot,
                             int co_off, int total) {
    int i = blockIdx.x * 256 + threadIdx.x;
    if (i >= total) return;
    int ci  = i % Cin;
    int tap = (i / Cin) % 9;
    int co  = i / (Cin * 9);
    dst[((size_t)tap * CoutTot + co_off + co) * Cin + ci] =
        f2bf(src[((size_t)co * Cin + ci) * 9 + tap] * scale[co]);
}

// 1x1: src fp32 [Co][Cin] -> dst bf16 [Co][Cin], scaled
__global__ void k_reorder_w1(const float* __restrict__ src, __hip_bfloat16* __restrict__ dst,
                             const float* __restrict__ scale, int Cin, int total) {
    int i = blockIdx.x * 256 + threadIdx.x;
    if (i >= total) return;
    dst[i] = f2bf(src[i] * scale[i / Cin]);
}

// ---------------- pools (NHWC bf16, C=64, in-place) ----------------

__global__ __launch_bounds__(256) void k_pool1(__hip_bfloat16* __restrict__ b) {
    const int idx = blockIdx.x * 256 + threadIdx.x; // 8*128*64 = 65536
    const int c = idx & 63;
    const int w = (idx >> 6) & 127;
    const int n = idx >> 13;
    const size_t stride = 128 * 64;
    const size_t base = ((size_t)n * 128 * 128 + w) * 64 + c;
    float m = 0.0f; // post-relu inputs are >= 0
    for (int hb = 31; hb >= 0; --hb) {
        size_t a0 = base + (size_t)(4 * hb) * stride;
        float v0 = bf2f(b[a0]);
        float v1 = bf2f(b[a0 + stride]);
        float v2 = bf2f(b[a0 + 2 * stride]);
        float v3 = bf2f(b[a0 + 3 * stride]);
        float m3 = fmaxf(m, v3);
        float m2 = fmaxf(m3, v2);
        float m1 = fmaxf(m2, v1);
        float m0 = fmaxf(m1, v0);
        b[a0 + 3 * stride] = f2bf(m3);
        b[a0 + 2 * stride] = f2bf(m2);
        b[a0 + stride]     = f2bf(m1);
        b[a0]              = f2bf(m0);
        m = m0;
    }
}

__global__ __launch_bounds__(256) void k_pool2(__hip_bfloat16* __restrict__ b,
                                               const __hip_bfloat16* __restrict__ pl) {
    const int idx = blockIdx.x * 256 + threadIdx.x;
    const int c = idx & 63;
    const int h = (idx >> 6) & 127;
    const int n = idx >> 13;
    const size_t base = (((size_t)n * 128 + h) * 128) * 64 + c;
    float m = 0.0f;
    for (int wb = 31; wb >= 0; --wb) {
        size_t a0 = base + (size_t)(4 * wb) * 64;
        float v0 = bf2f(b[a0]);
        float v1 = bf2f(b[a0 + 64]);
        float v2 = bf2f(b[a0 + 128]);
        float v3 = bf2f(b[a0 + 192]);
        float u0 = bf2f(pl[a0]);
        float u1 = bf2f(pl[a0 + 64]);
        float u2 = bf2f(pl[a0 + 128]);
        float u3 = bf2f(pl[a0 + 192]);
        float m3 = fmaxf(m, v3);
        float m2 = fmaxf(m3, v2);
        float m1 = fmaxf(m2, v1);
        float m0 = fmaxf(m1, v0);
        b[a0 + 192] = f2bf(m3 + u3);
        b[a0 + 128] = f2bf(m2 + u2);
        b[a0 + 64]  = f2bf(m1 + u1);
        b[a0]       = f2bf(m0 + u0);
        m = m0;
    }
}

// ---------------- 1x1 conv (res branch): GEMM 16384x256x256 ----------------
// D[p][co] = sum_ci X[p][ci]*W[co][ci]; out = D + bias (no relu), bf16 NHWC
__global__ __launch_bounds__(256) void conv1x1(const __hip_bfloat16* __restrict__ xin,
                                               const __hip_bfloat16* __restrict__ wgt,
                                               const float* __restrict__ bias,
                                               __hip_bfloat16* __restrict__ out) {
    __shared__ __align__(16) __hip_bfloat16 Xs[128 * 64];
    __shared__ __align__(16) __hip_bfloat16 Ws[128 * 64];
    const int tid  = threadIdx.x;
    const int lane = tid & 63;
    const int wid  = tid >> 6;
    const int wm = wid >> 1, wn = wid & 1;
    const int p0 = blockIdx.x * 128;
    const int c0 = blockIdx.y * 128;
    const int q = lane >> 4, r16 = lane & 15;

    floatx4 acc[4][4] = {};

    for (int k0 = 0; k0 < 256; k0 += 64) {
#pragma unroll
        for (int it = 0; it < 4; ++it) {
            const int pp = it * 32 + (tid >> 3);
            const int g  = tid & 7;
            uint4 val = *(const uint4*)(xin + ((size_t)(p0 + pp) * 256 + k0 + g * 8));
            *(uint4*)(&Xs[pp * 64 + (((g + pp) & 7) * 8)]) = val;
        }
#pragma unroll
        for (int it = 0; it < 4; ++it) {
            const int rr = it * 32 + (tid >> 3);
            const int g  = tid & 7;
            uint4 val = *(const uint4*)(wgt + ((size_t)(c0 + rr) * 256 + k0 + g * 8));
            *(uint4*)(&Ws[rr * 64 + (((g + rr) & 7) * 8)]) = val;
        }
        __syncthreads();
#pragma unroll
        for (int ks = 0; ks < 2; ++ks) {
            bf16x8 afr[4], bfr[4];
#pragma unroll
            for (int i = 0; i < 4; ++i) {
                const int pp = wm * 64 + i * 16 + r16;
                const int g  = ks * 4 + q;
                afr[i] = *(const bf16x8*)(&Xs[pp * 64 + (((g + pp) & 7) * 8)]);
            }
#pragma unroll
            for (int j = 0; j < 4; ++j) {
                const int rr = wn * 64 + j * 16 + r16;
                const int g  = ks * 4 + q;
                bfr[j] = *(const bf16x8*)(&Ws[rr * 64 + (((g + rr) & 7) * 8)]);
            }
#pragma unroll
            for (int i = 0; i < 4; ++i)
#pragma unroll
                for (int j = 0; j < 4; ++j)
                    acc[i][j] = __builtin_amdgcn_mfma_f32_16x16x32_bf16(afr[i], bfr[j], acc[i][j], 0, 0, 0);
        }
        __syncthreads();
    }
#pragma unroll
    for (int j = 0; j < 4; ++j) {
        const int co = c0 + wn * 64 + j * 16 + r16;
        const float bi = bias[co];
#pragma unroll
        for (int i = 0; i < 4; ++i) {
            const int pb = p0 + wm * 64 + i * 16 + q * 4;
#pragma unroll
            for (int r = 0; r < 4; ++r)
                out[(size_t)(pb + r) * 256 + co] = f2bf(acc[i][j][r] + bi);
        }
    }
}

// ---------------- halo-staged 3x3 conv ----------------
// p-tile = one image row (n,h): 128 w positions. For each 64-ci chunk, stage
// rows h-1,h,h+1 (w-halo entries 0 and 129 zeroed) ONCE, then run all 9 taps
// from LDS; per-tap only the 16KB W tile is restaged (L2-hot).
// MODE 1: +relu -> split bf16 NHWC out/out2 (co<64 -> out, else out2), COUT=128
// MODE 2: +bias +res, relu -> bf16 NHWC out, COUT=256
// MODE 3: +relu -> fp32 NCHW out (swapped operands, D[co][p]), COUT=256
template <int CIN, int COUT, int MODE>
__global__ __launch_bounds__(256) void conv3x3(const __hip_bfloat16* __restrict__ xin,
                                               const __hip_bfloat16* __restrict__ wgt,
                                               const float* __restrict__ bias,
                                               void* __restrict__ out,
                                               const __hip_bfloat16* __restrict__ resbuf,
                                               __hip_bfloat16* __restrict__ out2) {
    constexpr int NCHUNK = CIN / 64;
    __shared__ __align__(16) __hip_bfloat16 Xs[3][130][64]; // 48.75 KB, entries 0/129 = zero halo
    __shared__ __align__(16) __hip_bfloat16 Ws[128 * 64];   // 16 KB per-tap W tile
    const int tid  = threadIdx.x;
    const int lane = tid & 63;
    const int wid  = tid >> 6;
    const int wm = wid >> 1, wn = wid & 1;
    const int bx = blockIdx.x;            // 0..1023 = (n,h)
    const int n = bx >> 7, h = bx & 127;
    const int c0 = blockIdx.y * 128;
    const int p0 = bx * 128;
    const int q = lane >> 4, r16 = lane & 15;

    floatx4 acc[4][4] = {};

    // zero the w-halo entries (both sides, all 8 groups, 3 rows)
    if (tid < 48) {
        int r = tid >> 4, rem = tid & 15;
        int e = (rem >> 3) ? 129 : 0;
        int g = rem & 7;
        *(uint4*)(&Xs[r][e][g * 8]) = make_uint4(0u, 0u, 0u, 0u);
    }

    for (int c = 0; c < NCHUNK; ++c) {
        const int ci0 = c * 64;
        __syncthreads(); // prev chunk's compute done (covers halo zero on first iter)
        // stage X: 3 rows x 128 w x 64 ci
#pragma unroll
        for (int it = 0; it < 12; ++it) {
            int idx = it * 256 + tid;   // 0..3071
            int g = idx & 7;
            int w = (idx >> 3) & 127;
            int r = idx >> 10;          // 0..2
            int hh = h + r - 1;
            uint4 val = make_uint4(0u, 0u, 0u, 0u);
            if ((unsigned)hh < 128u)
                val = *(const uint4*)(xin + (((size_t)(n * 128 + hh) * 128 + w) * CIN + ci0 + g * 8));
            int e = w + 1;
            *(uint4*)(&Xs[r][e][((g + e) & 7) * 8]) = val;
        }
#pragma unroll
        for (int tap = 0; tap < 9; ++tap) {
            if (tap > 0) __syncthreads(); // prev tap done reading Ws
            // stage W tile [128 co][64 ci] for this tap
#pragma unroll
            for (int it = 0; it < 4; ++it) {
                int idx = it * 256 + tid;
                int g = idx & 7, rr = idx >> 3;
                uint4 val = *(const uint4*)(wgt + ((size_t)(tap * COUT + c0 + rr) * CIN) + ci0 + g * 8);
                *(uint4*)(&Ws[rr * 64 + ((g + rr) & 7) * 8]) = val;
            }
            __syncthreads();
            const int r  = tap / 3;       // row select
            const int dw = tap % 3 - 1;   // w shift
#pragma unroll
            for (int ks = 0; ks < 2; ++ks) {
                bf16x8 afr[4], bfr[4];
#pragma unroll
                for (int i = 0; i < 4; ++i) {
                    int e = wm * 64 + i * 16 + r16 + dw + 1; // 0..129
                    int g = ks * 4 + q;
                    afr[i] = *(const bf16x8*)(&Xs[r][e][((g + e) & 7) * 8]);
                }
#pragma unroll
                for (int j = 0; j < 4; ++j) {
                    int rr = wn * 64 + j * 16 + r16;
                    int g  = ks * 4 + q;
                    bfr[j] = *(const bf16x8*)(&Ws[rr * 64 + ((g + rr) & 7) * 8]);
                }
#pragma unroll
                for (int i = 0; i < 4; ++i)
#pragma unroll
                    for (int j = 0; j < 4; ++j) {
                        if (MODE == 3)
                            acc[i][j] = __builtin_amdgcn_mfma_f32_16x16x32_bf16(bfr[i], afr[j], acc[i][j], 0, 0, 0);
                        else
                            acc[i][j] = __builtin_amdgcn_mfma_f32_16x16x32_bf16(afr[i], bfr[j], acc[i][j], 0, 0, 0);
                    }
            }
        }
    }

    if (MODE == 1) {
#pragma unroll
        for (int j = 0; j < 4; ++j) {
            const int co = wn * 64 + j * 16 + r16; // 0..127
            const float bi = bias[co];
            __hip_bfloat16* ob = (co < 64) ? (__hip_bfloat16*)out : out2;
            const int ch = co & 63;
#pragma unroll
            for (int i = 0; i < 4; ++i) {
                const int pb = p0 + wm * 64 + i * 16 + q * 4;
#pragma unroll
                for (int r = 0; r < 4; ++r)
                    ob[(size_t)(pb + r) * 64 + ch] = f2bf(fmaxf(acc[i][j][r] + bi, 0.0f));
            }
        }
    } else if (MODE == 2) {
        __hip_bfloat16* o = (__hip_bfloat16*)out;
#pragma unroll
        for (int j = 0; j < 4; ++j) {
            const int co = c0 + wn * 64 + j * 16 + r16;
            const float bi = bias[co];
#pragma unroll
            for (int i = 0; i < 4; ++i) {
                const int pb = p0 + wm * 64 + i * 16 + q * 4;
#pragma unroll
                for (int r = 0; r < 4; ++r) {
                    float v = acc[i][j][r] + bi + bf2f(resbuf[(size_t)(pb + r) * 256 + co]);
                    o[(size_t)(pb + r) * 256 + co] = f2bf(fmaxf(v, 0.0f));
                }
            }
        }
    } else { // MODE 3: fp32 NCHW
        float* o = (float*)out;
#pragma unroll
        for (int i = 0; i < 4; ++i) {
#pragma unroll
            for (int r = 0; r < 4; ++r) {
                const int co = c0 + wn * 64 + i * 16 + q * 4 + r;
                const float bi = bias[co];
#pragma unroll
                for (int j = 0; j < 4; ++j) {
                    const int w = wm * 64 + j * 16 + r16;
                    float v = fmaxf(acc[i][j][r] + bi, 0.0f);
                    o[(((size_t)(n * 256 + co)) * 128 + h) * 128 + w] = v;
                }
            }
        }
    }
}

// ---------------- launcher ----------------

extern "C" void kernel_launch(void* const* d_in, const int* in_sizes, int n_in,
                              void* d_out, int out_size, void* d_ws, size_t ws_size,
                              hipStream_t stream) {
    const float* x       = (const float*)d_in[0];
    const float* w_res   = (const float*)d_in[1];
    const float* bn_res  = (const float*)d_in[2];
    const float* w_vpre  = (const float*)d_in[3];
    const float* bn_vpre = (const float*)d_in[4];
    const float* w_hpre  = (const float*)d_in[5];
    const float* bn_hpre = (const float*)d_in[6];
    const float* w_add   = (const float*)d_in[7];
    const float* bn_add  = (const float*)d_in[8];
    const float* w_post  = (const float*)d_in[9];
    const float* bn_post = (const float*)d_in[10];

    const size_t SZ_XB = (size_t)8 * 128 * 128 * 256 * 2; // 67,108,864
    const size_t SZ_P  = (size_t)8 * 128 * 128 * 64 * 2;  // 16,777,216

    char* w = (char*)d_ws;
    __hip_bfloat16* xb   = (__hip_bfloat16*)(w);          // reused as add-conv output
    __hip_bfloat16* resb = (__hip_bfloat16*)(w + SZ_XB);
    __hip_bfloat16* p1   = (__hip_bfloat16*)(w + 2 * SZ_XB);
    __hip_bfloat16* p2   = (__hip_bfloat16*)(w + 2 * SZ_XB + SZ_P);
    char* wp = w + 2 * SZ_XB + 2 * SZ_P;
    __hip_bfloat16* wres  = (__hip_bfloat16*)wp; wp += (size_t)65536 * 2;        // [256][256]
    __hip_bfloat16* wpre  = (__hip_bfloat16*)wp; wp += (size_t)9 * 128 * 256 * 2; // [9][128][256]
    __hip_bfloat16* wadd  = (__hip_bfloat16*)wp; wp += (size_t)9 * 256 * 64 * 2;  // [9][256][64]
    __hip_bfloat16* wpost = (__hip_bfloat16*)wp; wp += (size_t)9 * 256 * 256 * 2; // [9][256][256]
    float* sc_res  = (float*)wp; wp += 256 * 4;
    float* bi_res  = (float*)wp; wp += 256 * 4;
    float* sc_pre  = (float*)wp; wp += 128 * 4;
    float* bi_pre  = (float*)wp; wp += 128 * 4;
    float* sc_add  = (float*)wp; wp += 256 * 4;
    float* bi_add  = (float*)wp; wp += 256 * 4;
    float* sc_post = (float*)wp; wp += 256 * 4;
    float* bi_post = (float*)wp; wp += 256 * 4;

    // BN prep first (reorder kernels consume the scales)
    k_prep_bn<<<4, 64, 0, stream>>>(bn_res, sc_res, bi_res, 256);
    k_prep_bn<<<1, 64, 0, stream>>>(bn_vpre, sc_pre, bi_pre, 64);
    k_prep_bn<<<1, 64, 0, stream>>>(bn_hpre, sc_pre + 64, bi_pre + 64, 64);
    k_prep_bn<<<4, 64, 0, stream>>>(bn_add, sc_add, bi_add, 256);
    k_prep_bn<<<4, 64, 0, stream>>>(bn_post, sc_post, bi_post, 256);

    // weight reorder + BN-scale fold
    k_reorder_w1<<<256, 256, 0, stream>>>(w_res, wres, sc_res, 256, 65536);
    k_reorder_w3<<<576, 256, 0, stream>>>(w_vpre, wpre, sc_pre, 256, 128, 0, 147456);
    k_reorder_w3<<<576, 256, 0, stream>>>(w_hpre, wpre, sc_pre + 64, 256, 128, 64, 147456);
    k_reorder_w3<<<576, 256, 0, stream>>>(w_add, wadd, sc_add, 64, 256, 0, 147456);
    k_reorder_w3<<<2304, 256, 0, stream>>>(w_post, wpost, sc_post, 256, 256, 0, 589824);

    // x -> NHWC bf16
    k_cast_x<<<dim3(8, 128, 8), 256, 0, stream>>>(x, xb);

    // res = conv1x1(x)*s + b -> resb
    conv1x1<<<dim3(1024, 2), 256, 0, stream>>>(xb, wres, bi_res, resb);
    // fused vpre+hpre: relu(conv3x3(x)) -> p1 (co 0..63), p2 (co 64..127)
    conv3x3<256, 128, 1><<<dim3(1024, 1), 256, 0, stream>>>(xb, wpre, bi_pre, p1, nullptr, p2);
    // pools: p1 = TopPool(p1); p2 = LeftPool(p2) + p1
    k_pool1<<<256, 256, 0, stream>>>(p1);
    k_pool2<<<256, 256, 0, stream>>>(p2, p1);
    // merged + res, relu -> xb
    conv3x3<64, 256, 2><<<dim3(1024, 2), 256, 0, stream>>>(p2, wadd, bi_add, xb, resb, nullptr);
    // post conv: relu -> d_out fp32 NCHW
    conv3x3<256, 256, 3><<<dim3(1024, 2), 256, 0, stream>>>(xb, wpost, bi_post, d_out, nullptr, nullptr);
}